// Round 4
// baseline (429.776 us; speedup 1.0000x reference)
//
#include <hip/hip_runtime.h>
#include <math.h>

#define BB 8
#define SS 8192
#define DD 512
#define HH 256
#define MM (BB * SS)        // 65536 rows
#define CC 64               // chunks per sequence
#define LL 128              // chunk length

typedef unsigned short u16;
typedef unsigned int u32;
typedef __attribute__((ext_vector_type(8))) short short8;   // 8 bf16 = MFMA A/B frag
typedef __attribute__((ext_vector_type(4))) float f32x4;    // MFMA C/D frag

__device__ __forceinline__ u16 f2bf_rtne(float f) {
    union { float f; unsigned u; } v; v.f = f;
    unsigned r = v.u + 0x7fffu + ((v.u >> 16) & 1u);
    return (u16)(r >> 16);
}
// pack two floats -> u32 of two bf16 (round-to-nearest): low16 = a, high16 = b
__device__ __forceinline__ u32 pack2_rtn(float a, float b) {
    union { float f; unsigned u; } x, y; x.f = a; y.f = b;
    return ((x.u + 0x8000u) >> 16) | ((y.u + 0x8000u) & 0xffff0000u);
}
__device__ __forceinline__ float bf_lo(u32 w) { return __uint_as_float(w << 16); }
__device__ __forceinline__ float bf_hi(u32 w) { return __uint_as_float(w & 0xffff0000u); }

__device__ __forceinline__ float sp_fast(float z) {    // softplus
    return (z > 15.0f) ? z : __logf(1.0f + __expf(z));
}

// ---- W fp32 [3H,D] -> Wr bf16 [768,512] row-major k-contiguous, rows reordered:
//      orow = hg*48 + g*16 + hl  <-  irow = g*256 + hg*16 + hl
__global__ __launch_bounds__(128) void convert_W(const float* __restrict__ W,
                                                 u16* __restrict__ Wr) {
    const int orow = blockIdx.x;            // 0..767
    const int hg = orow / 48, rem = orow % 48;
    const int g = rem >> 4, hl = rem & 15;
    const int irow = g * HH + hg * 16 + hl;
    const int t = threadIdx.x;              // 128 threads x 4 elems
    const float4 v = *(const float4*)&W[(size_t)irow * DD + t * 4];
    ushort4 o;
    o.x = f2bf_rtne(v.x); o.y = f2bf_rtne(v.y); o.z = f2bf_rtne(v.z); o.w = f2bf_rtne(v.w);
    *(ushort4*)&Wr[(size_t)orow * DD + t * 4] = o;
}

// ---- Fused GEMM + gates + chunk-local scan partials.
// Grid 1024 blocks (64 rows each), 512 threads (8 waves). NO LDS, NO barriers.
// Wave w owns cols w*96 .. w*96+95 (= head-groups 2w, 2w+1; within 48: f|i|h x16).
// A and B fragments loaded straight into VGPRs.
__global__ __launch_bounds__(512, 2) void gemm_gate_scan(
    const float* __restrict__ x,      // [M,512] fp32
    const u16* __restrict__ Wr,       // [768,512] bf16 reordered
    u32* __restrict__ FU,             // [M,H] packed (F lo, u hi)
    u32* __restrict__ PU)             // [B, 128, H] per-64-row scan partials (P lo, U hi)
{
    const int tid = threadIdx.x;
    const int w = tid >> 6;           // wave 0..7
    const int lane = tid & 63;
    const int l16 = lane & 15;
    const int quad = lane >> 4;       // 0..3
    const int m0 = blockIdx.x * 64;

    const float* xp = x + (size_t)(m0 + l16) * DD + quad * 8;
    const u16* wp = Wr + (size_t)(w * 96 + l16) * DD + quad * 8;

    f32x4 acc[4][6];
    #pragma unroll
    for (int a = 0; a < 4; ++a)
        #pragma unroll
        for (int b = 0; b < 6; ++b)
            #pragma unroll
            for (int e = 0; e < 4; ++e) acc[a][b][e] = 0.0f;

    short8 ca[4], cb[6];
    // load ks=0
    #pragma unroll
    for (int mf = 0; mf < 4; ++mf) {
        const float4 v0 = *(const float4*)(xp + (size_t)mf * 16 * DD);
        const float4 v1 = *(const float4*)(xp + (size_t)mf * 16 * DD + 4);
        u32 q[4] = { pack2_rtn(v0.x, v0.y), pack2_rtn(v0.z, v0.w),
                     pack2_rtn(v1.x, v1.y), pack2_rtn(v1.z, v1.w) };
        ca[mf] = *(const short8*)q;
    }
    #pragma unroll
    for (int nf = 0; nf < 6; ++nf)
        cb[nf] = *(const short8*)(wp + (size_t)nf * 16 * DD);

    #pragma unroll
    for (int ks = 0; ks < 16; ++ks) {
        short8 na[4], nb[6];
        if (ks < 15) {
            const int ko = (ks + 1) * 32;
            #pragma unroll
            for (int mf = 0; mf < 4; ++mf) {
                const float4 v0 = *(const float4*)(xp + (size_t)mf * 16 * DD + ko);
                const float4 v1 = *(const float4*)(xp + (size_t)mf * 16 * DD + ko + 4);
                u32 q[4] = { pack2_rtn(v0.x, v0.y), pack2_rtn(v0.z, v0.w),
                             pack2_rtn(v1.x, v1.y), pack2_rtn(v1.z, v1.w) };
                na[mf] = *(const short8*)q;
            }
            #pragma unroll
            for (int nf = 0; nf < 6; ++nf)
                nb[nf] = *(const short8*)(wp + (size_t)nf * 16 * DD + ko);
        }
        #pragma unroll
        for (int mf = 0; mf < 4; ++mf)
            #pragma unroll
            for (int nf = 0; nf < 6; ++nf)
                acc[mf][nf] = __builtin_amdgcn_mfma_f32_16x16x32_bf16(
                    ca[mf], cb[nf], acc[mf][nf], 0, 0, 0);
        if (ks < 15) {
            #pragma unroll
            for (int mf = 0; mf < 4; ++mf) ca[mf] = na[mf];
            #pragma unroll
            for (int nf = 0; nf < 6; ++nf) cb[nf] = nb[nf];
        }
    }

    // ---- epilogue: gates + FU store + ordered scan-compose over the 64 rows ----
    // per mf: 16 rows (t = quad*4 + r); compose in-lane over r, butterfly over quads.
    float Pg[2], Ug[2];               // running group compose across mf (per head-group)
    #pragma unroll
    for (int hg = 0; hg < 2; ++hg) { Pg[hg] = 1.0f; Ug[hg] = 0.0f; }

    #pragma unroll
    for (int mf = 0; mf < 4; ++mf) {
        float P[2] = {1.0f, 1.0f}, U[2] = {0.0f, 0.0f};
        #pragma unroll
        for (int r = 0; r < 4; ++r) {
            const int m = m0 + mf * 16 + quad * 4 + r;
            #pragma unroll
            for (int hg = 0; hg < 2; ++hg) {
                const float fr = acc[mf][hg * 3 + 0][r];
                const float ir = acc[mf][hg * 3 + 1][r];
                const float hr = acc[mf][hg * 3 + 2][r];
                const float diff = sp_fast(-fr) - sp_fast(-ir);
                const float F = __builtin_amdgcn_rcpf(1.0f + __expf(diff));  // sigmoid(-diff)
                const float I = 1.0f - F;
                const float G = (hr >= 0.0f) ? (hr + 0.5f)
                                             : __builtin_amdgcn_rcpf(1.0f + __expf(-hr));
                const float u = I * G;
                FU[(size_t)m * HH + (2 * w + hg) * 16 + l16] = pack2_rtn(F, u);
                U[hg] = U[hg] * F + u;
                P[hg] = P[hg] * F;
            }
        }
        // ordered butterfly across quads (t order = quad ascending)
        #pragma unroll
        for (int s = 0; s < 2; ++s) {
            const int mask = 16 << s;
            const bool late = (s == 0) ? (quad & 1) : ((quad >> 1) & 1);
            #pragma unroll
            for (int hg = 0; hg < 2; ++hg) {
                const float oP = __shfl_xor(P[hg], mask, 64);
                const float oU = __shfl_xor(U[hg], mask, 64);
                const float eP = late ? oP : P[hg];
                const float eU = late ? oU : U[hg];
                const float lP = late ? P[hg] : oP;
                const float lU = late ? U[hg] : oU;
                P[hg] = eP * lP;
                U[hg] = eU * lP + lU;
            }
        }
        // fold this 16-row segment into the 64-row group compose (mf ascending = t order)
        #pragma unroll
        for (int hg = 0; hg < 2; ++hg) {
            Ug[hg] = Ug[hg] * P[hg] + U[hg];
            Pg[hg] = Pg[hg] * P[hg];
        }
    }
    if (lane < 16) {
        const int b = m0 >> 13;                 // /8192
        const int grp = (m0 & 8191) >> 6;       // 64-row group within sequence
        #pragma unroll
        for (int hg = 0; hg < 2; ++hg)
            PU[((size_t)b * 128 + grp) * HH + (2 * w + hg) * 16 + l16] =
                pack2_rtn(Pg[hg], Ug[hg]);
    }
}

// ---- pass2: sequential compose of 128 per-64-row partials per (b,h); emits
//      chunk-entry carries Hin[c][b][h] (chunk = 2 groups = 128 t).
__global__ __launch_bounds__(256) void scan_pass2(
    const float* __restrict__ h_prev, const u32* __restrict__ PU,
    float* __restrict__ Hin) {
    const int b = blockIdx.x;
    const int h = threadIdx.x;
    const float z = h_prev[b * HH + h];
    float carry = (z >= 0.0f) ? (z + 0.5f) : __builtin_amdgcn_rcpf(1.0f + __expf(-z));
    #pragma unroll 8
    for (int grp = 0; grp < 128; ++grp) {
        if ((grp & 1) == 0)
            Hin[((size_t)(grp >> 1) * BB + b) * HH + h] = carry;
        const u32 pu = PU[((size_t)b * 128 + grp) * HH + h];
        carry = bf_lo(pu) * carry + bf_hi(pu);
    }
}

// ---- pass3: final within-chunk recurrence, writes h_t ----
__global__ __launch_bounds__(256) void scan_pass3(
    const u32* __restrict__ FU, const float* __restrict__ Hin,
    float* __restrict__ out) {
    const int bc = blockIdx.x;
    const int b = bc / CC;
    const int c = bc % CC;
    const int h = threadIdx.x;
    float hv = Hin[((size_t)c * BB + b) * HH + h];
    size_t base = ((size_t)(b * SS + c * LL)) * HH + h;
    #pragma unroll 4
    for (int t = 0; t < LL; ++t) {
        const u32 fu = FU[base];
        hv = bf_lo(fu) * hv + bf_hi(fu);
        out[base] = hv;
        base += HH;
    }
}

extern "C" void kernel_launch(void* const* d_in, const int* in_sizes, int n_in,
                              void* d_out, int out_size, void* d_ws, size_t ws_size,
                              hipStream_t stream) {
    const float* x      = (const float*)d_in[0];   // [B,S,D]
    const float* h_prev = (const float*)d_in[1];   // [B,H]
    const float* W      = (const float*)d_in[2];   // [3H,D]

    // ws: FU [M*H] u32 (67 MB) | Hin [C*B*H] f32 (0.5 MB) | Wr [768*512] bf16 (0.77 MB)
    u32*   FU  = (u32*)d_ws;
    float* Hin = (float*)(FU + (size_t)MM * HH);
    u16*   Wr  = (u16*)(Hin + (size_t)CC * BB * HH);
    // PU partials (1 MB) live at the start of d_out; fully consumed by pass2
    // before pass3 overwrites d_out.
    u32*   PU  = (u32*)d_out;

    convert_W<<<768, 128, 0, stream>>>(W, Wr);
    gemm_gate_scan<<<MM / 64, 512, 0, stream>>>(x, Wr, FU, PU);
    scan_pass2<<<BB, HH, 0, stream>>>(h_prev, PU, Hin);
    scan_pass3<<<BB * CC, HH, 0, stream>>>(FU, Hin, (float*)d_out);
}